// Round 1
// baseline (72.915 us; speedup 1.0000x reference)
//
#include <hip/hip_runtime.h>

// GravityMCDecoder: per-edge pairwise-distance decoder.
// Reference builds the full 12288^2 adjacency then gathers 262144 edges;
// we compute only the needed entries: d2(u,v) is symmetric, so one 64-dim
// squared distance per edge feeds both logits.

constexpr int kNodes = 12288;
constexpr int kD     = 64;    // D_PLUS_1 - 1
constexpr int kRow   = 65;    // row stride of z in floats
constexpr int kEdges = 262144;
constexpr float kEps = 0.01f;

// 16 lanes per edge; 4 edges per wave; block=256 -> 16 edges per block-iter.
// Lane s covers dims [4s, 4s+3]; across 16 lanes that's 64 contiguous floats
// (256 B) per row -> full cache-line consumption despite the random row gather.
__global__ __launch_bounds__(256) void edge_kernel(
    const float* __restrict__ z,
    const float* __restrict__ lptr,
    const int*   __restrict__ eidx,   // [2, kEdges] row-major: u's then v's
    float4*      __restrict__ out)    // [kEdges] = (p_nb, p_pu, p_pb, p_nu)
{
    const float l = lptr[0];
    const int tid = blockIdx.x * blockDim.x + threadIdx.x;
    const int sub = tid & 15;                       // lane within edge group
    const int estride = (gridDim.x * blockDim.x) >> 4;

    for (int e = tid >> 4; e < kEdges; e += estride) {
        const int u = eidx[e];
        const int v = eidx[kEdges + e];
        const float* zu = z + (long)u * kRow + sub * 4;
        const float* zv = z + (long)v * kRow + sub * 4;

        float p = 0.f;
#pragma unroll
        for (int j = 0; j < 4; ++j) {
            const float d = zu[j] - zv[j];
            p = fmaf(d, d, p);
        }
        // butterfly sum across the 16-lane group (masks < 16 stay in-group)
        p += __shfl_xor(p, 1);
        p += __shfl_xor(p, 2);
        p += __shfl_xor(p, 4);
        p += __shfl_xor(p, 8);

        if (sub == 0) {
            const float logd     = __logf(p + kEps);
            const float logit_uv = z[(long)v * kRow + kD] - l * logd;  // m[v] - l*log r2
            const float logit_vu = z[(long)u * kRow + kD] - l * logd;  // m[u] - l*log r2
            const float suv = 1.f / (1.f + __expf(-logit_uv));
            const float svu = 1.f / (1.f + __expf(-logit_vu));
            out[e] = make_float4((1.f - suv) * (1.f - svu),   // p_nb
                                 suv         * (1.f - svu),   // p_pu
                                 suv         * svu,           // p_pb
                                 (1.f - suv) * svu);          // p_nu
        }
    }
}

extern "C" void kernel_launch(void* const* d_in, const int* in_sizes, int n_in,
                              void* d_out, int out_size, void* d_ws, size_t ws_size,
                              hipStream_t stream) {
    const float* z    = (const float*)d_in[0];
    const float* lptr = (const float*)d_in[1];
    const int*   eidx = (const int*)d_in[2];
    float4*      out  = (float4*)d_out;

    // 4096 blocks * 256 thr / 16 lanes-per-edge = 65536 edge slots -> 4 iters.
    edge_kernel<<<dim3(4096), dim3(256), 0, stream>>>(z, lptr, eidx, out);
}